// Round 10
// baseline (170413.440 us; speedup 1.0000x reference)
//
#include <hip/hip_runtime.h>
#include <stdint.h>

#define T_STEPS 32768
#define HDIM    1024
#define LDIM    512
#define ADIM    32
#define NWG     256   // one single-wave WG per CU
#define NOUT    4     // outputs per WG (NWG*NOUT == HDIM)

__device__ __forceinline__ float fast_sigmoid(float x) {
    float e = __expf(-x);
    return __builtin_amdgcn_rcpf(1.0f + e);
}
__device__ __forceinline__ float fast_tanh(float x) {
    // tanh(x) = 1 - 2/(1+e^(2x)); exact at +-inf, ~2ulp elsewhere
    float e = __expf(2.0f * x);
    return 1.0f - 2.0f * __builtin_amdgcn_rcpf(1.0f + e);
}

// ---------------------------------------------------------------------------
// Encoder: z[t,m] = tanh( sum_k obs[t,k]*enc_w[m,k] + enc_b[m] )
// ---------------------------------------------------------------------------
__global__ __launch_bounds__(256) void encoder_kernel(
    const float* __restrict__ obs,    // (T,128)
    const float* __restrict__ w,      // (512,128)
    const float* __restrict__ b,      // (512)
    float* __restrict__ z)            // (T,512)
{
    __shared__ float As[64][65];
    __shared__ float Bs[64][65];

    const int tile_n = blockIdx.x;  // 0..7   (m tiles)
    const int tile_t = blockIdx.y;  // 0..511 (t tiles)
    const int tid = threadIdx.x;
    const int ty = tid >> 4;
    const int tx = tid & 15;

    float acc[4][4] = {};

    for (int kt = 0; kt < 2; ++kt) {
        #pragma unroll
        for (int it = 0; it < 4; ++it) {
            int lin = it * 1024 + tid * 4;
            int r = lin >> 6, c = lin & 63;
            float4 va = *(const float4*)&obs[(size_t)(tile_t * 64 + r) * 128 + kt * 64 + c];
            As[r][c] = va.x; As[r][c+1] = va.y; As[r][c+2] = va.z; As[r][c+3] = va.w;
            float4 vb = *(const float4*)&w[(size_t)(tile_n * 64 + r) * 128 + kt * 64 + c];
            Bs[r][c] = vb.x; Bs[r][c+1] = vb.y; Bs[r][c+2] = vb.z; Bs[r][c+3] = vb.w;
        }
        __syncthreads();

        for (int k = 0; k < 64; ++k) {
            float av[4], bv[4];
            #pragma unroll
            for (int a = 0; a < 4; ++a) av[a] = As[ty * 4 + a][k];
            #pragma unroll
            for (int c = 0; c < 4; ++c) bv[c] = Bs[tx * 4 + c][k];
            #pragma unroll
            for (int a = 0; a < 4; ++a)
                #pragma unroll
                for (int c = 0; c < 4; ++c)
                    acc[a][c] = fmaf(av[a], bv[c], acc[a][c]);
        }
        __syncthreads();
    }

    #pragma unroll
    for (int a = 0; a < 4; ++a) {
        int row = tile_t * 64 + ty * 4 + a;
        #pragma unroll
        for (int c = 0; c < 4; ++c) {
            int col = tile_n * 64 + tx * 4 + c;
            z[(size_t)row * LDIM + col] = tanhf(acc[a][c] + b[col]);
        }
    }
}

// ---------------------------------------------------------------------------
// GRU recurrence — barrier-free single-wave WGs (R9 concept, bisected).
// Changes vs failed R9, exactly two:
//  1. NORMAL launch <<<256,64>>> (cooperative-launch failure was suspect (a);
//     co-residency is guaranteed by capacity: __launch_bounds__(64,1) caps
//     VGPR at 512 -> >=1 wave/SIMD -> >=4 blocks/CU -> capacity 1024 >= 256,
//     so all 256 blocks are resident immediately; spin protocol is safe).
//  2. SIMPLE reduce + permutation-free publication (transpose-butterfly/myc
//     machinery was suspect (b)): full 64-lane butterfly on all 16
//     accumulators; lane selects its class output oc=lane&3 via a
//     compile-time select chain; lanes 0..3 publish slot lane (= output
//     obase+lane) in one coalesced 32B tagged store.
// Everything else (polling layout, tag-in-data, parity double buffer,
// register-resident weights, gates) is byte-identical to R9.
// ---------------------------------------------------------------------------
__global__ __launch_bounds__(64, 1) void gru_kernel(
    float* __restrict__ out,          // (T, 1024) == beliefs
    const float* __restrict__ z_seq,  // (T, 512)
    const float* __restrict__ act,    // (T, 32)
    const float* __restrict__ w_ih,   // (3072, 544)
    const float* __restrict__ w_hh,   // (3072, 1024)
    const float* __restrict__ b_ih,   // (3072)
    const float* __restrict__ b_hh,   // (3072)
    uint64_t* __restrict__ hbuf)      // (2, 256, 8) packed, zeroed
{
    const int lane  = threadIdx.x;    // 0..63
    const int wg    = blockIdx.x;     // 0..255
    const int obase = wg * NOUT;

    // ---- load weight slices into registers (once) and PIN them ----
    // hh: whh[g][o][m][c] = w_hh[(g*1024 + obase+o)][256m + 4*lane + c]
    float whh[3][4][4][4];
    #pragma unroll
    for (int g = 0; g < 3; ++g)
        #pragma unroll
        for (int o = 0; o < 4; ++o) {
            const float* row = &w_hh[(size_t)(g * HDIM + obase + o) * HDIM];
            #pragma unroll
            for (int m = 0; m < 4; ++m)
                #pragma unroll
                for (int c = 0; c < 4; ++c)
                    whh[g][o][m][c] = row[m * 256 + lane * 4 + c];
        }
    // ih (z part): wz[g][o][j] = w_ih[(g*1024 + obase+o)][8*lane + j]
    float wz[3][4][8];
    #pragma unroll
    for (int g = 0; g < 3; ++g)
        #pragma unroll
        for (int o = 0; o < 4; ++o) {
            const float* row = &w_ih[(size_t)(g * HDIM + obase + o) * 544];
            #pragma unroll
            for (int j = 0; j < 8; ++j)
                wz[g][o][j] = row[lane * 8 + j];
        }
    // ih (act part): lane j<32 handles act col j
    float wa[3][4];
    #pragma unroll
    for (int g = 0; g < 3; ++g)
        #pragma unroll
        for (int o = 0; o < 4; ++o)
            wa[g][o] = (lane < ADIM)
                ? w_ih[(size_t)(g * HDIM + obase + o) * 544 + LDIM + lane] : 0.0f;

    // opaque-pin all weights (compiler must not re-fetch per step)
    #pragma unroll
    for (int g = 0; g < 3; ++g)
        #pragma unroll
        for (int o = 0; o < 4; ++o) {
            #pragma unroll
            for (int m = 0; m < 4; ++m)
                #pragma unroll
                for (int c = 0; c < 4; ++c)
                    asm volatile("" : "+v"(whh[g][o][m][c]));
            #pragma unroll
            for (int j = 0; j < 8; ++j)
                asm volatile("" : "+v"(wz[g][o][j]));
            asm volatile("" : "+v"(wa[g][o]));
        }

    // natural-order output class: lane l belongs to output obase + (l&3)
    const int oc  = lane & 3;
    const int myo = obase + oc;
    const float bias_r = b_ih[myo] + b_hh[myo];
    const float bias_z = b_ih[HDIM + myo] + b_hh[HDIM + myo];
    const float bin_   = b_ih[2 * HDIM + myo];
    const float bhn    = b_hh[2 * HDIM + myo];

    float hold = 0.0f;

    for (int t = 0; t < T_STEPS; ++t) {
        // ---- input loads for this step (overlap the poll rounds) ----
        float4 z0 = *(const float4*)&z_seq[(size_t)t * LDIM + lane * 8];
        float4 z1 = *(const float4*)&z_seq[(size_t)t * LDIM + lane * 8 + 4];
        float av = 0.0f;
        if (t > 0 && lane < ADIM) av = act[(size_t)(t - 1) * ADIM + lane];

        // ---- poll h(t-1) into registers: 4 lines x 4 tagged words ----
        float h[4][4];
        if (t == 0) {
            #pragma unroll
            for (int m = 0; m < 4; ++m)
                #pragma unroll
                for (int c = 0; c < 4; ++c) h[m][c] = 0.0f;
        } else {
            const uint64_t* bp = hbuf + ((size_t)((t - 1) & 1)) * (NWG * 8);
            const uint32_t want = (uint32_t)t;
            uint64_t v[4][4];
            int done = 0;
            while (done != 0xF) {
                #pragma unroll
                for (int m = 0; m < 4; ++m) {
                    if (!(done & (1 << m))) {
                        const uint64_t* lp = bp + (size_t)(m * 64 + lane) * 8;
                        #pragma unroll
                        for (int c = 0; c < 4; ++c)
                            v[m][c] = __hip_atomic_load(lp + c, __ATOMIC_RELAXED,
                                                        __HIP_MEMORY_SCOPE_AGENT);
                    }
                }
                #pragma unroll
                for (int m = 0; m < 4; ++m) {
                    if (!(done & (1 << m))) {
                        bool ok = true;
                        #pragma unroll
                        for (int c = 0; c < 4; ++c)
                            ok = ok && ((uint32_t)(v[m][c] >> 32) == want);
                        if (ok) done |= (1 << m);
                    }
                }
            }
            #pragma unroll
            for (int m = 0; m < 4; ++m)
                #pragma unroll
                for (int c = 0; c < 4; ++c)
                    h[m][c] = __uint_as_float((uint32_t)v[m][c]);
        }

        // ---- per-lane partial matvec: 4 outputs x {vr, vz, sn(hh), gn(ih)} ----
        float ar[4] = {}, az[4] = {}, anh[4] = {}, ani[4] = {};
        float zv[8] = {z0.x, z0.y, z0.z, z0.w, z1.x, z1.y, z1.z, z1.w};
        #pragma unroll
        for (int o = 0; o < 4; ++o) {
            #pragma unroll
            for (int m = 0; m < 4; ++m)
                #pragma unroll
                for (int c = 0; c < 4; ++c) {
                    float hv = h[m][c];
                    ar[o]  = fmaf(whh[0][o][m][c], hv, ar[o]);
                    az[o]  = fmaf(whh[1][o][m][c], hv, az[o]);
                    anh[o] = fmaf(whh[2][o][m][c], hv, anh[o]);
                }
            #pragma unroll
            for (int j = 0; j < 8; ++j) {
                ar[o]  = fmaf(wz[0][o][j], zv[j], ar[o]);
                az[o]  = fmaf(wz[1][o][j], zv[j], az[o]);
                ani[o] = fmaf(wz[2][o][j], zv[j], ani[o]);
            }
            ar[o]  = fmaf(wa[0][o], av, ar[o]);
            az[o]  = fmaf(wa[1][o], av, az[o]);
            ani[o] = fmaf(wa[2][o], av, ani[o]);
        }

        // ---- SIMPLE full-wave butterfly on all 16 accumulators ----
        #pragma unroll
        for (int o = 0; o < 4; ++o) {
            #pragma unroll
            for (int m = 1; m <= 32; m <<= 1) {
                ar[o]  += __shfl_xor(ar[o],  m);
                az[o]  += __shfl_xor(az[o],  m);
                anh[o] += __shfl_xor(anh[o], m);
                ani[o] += __shfl_xor(ani[o], m);
            }
        }
        // compile-time select chain (no runtime array index -> no scratch)
        float s_r  = (oc == 0) ? ar[0]  : (oc == 1) ? ar[1]  : (oc == 2) ? ar[2]  : ar[3];
        float s_z  = (oc == 0) ? az[0]  : (oc == 1) ? az[1]  : (oc == 2) ? az[2]  : az[3];
        float s_nh = (oc == 0) ? anh[0] : (oc == 1) ? anh[1] : (oc == 2) ? anh[2] : anh[3];
        float s_ni = (oc == 0) ? ani[0] : (oc == 1) ? ani[1] : (oc == 2) ? ani[2] : ani[3];

        // ---- gates (all lanes; identical within a lane class) ----
        float r    = fast_sigmoid(s_r + bias_r);
        float zg   = fast_sigmoid(s_z + bias_z);
        float n    = fast_tanh(s_ni + bin_ + r * (s_nh + bhn));
        float hnew = (1.0f - zg) * n + zg * hold;
        hold = hnew;

        // ---- publication: lanes 0..3 (oc==lane) -> one 32B tagged store ----
        if (lane < 4) {
            uint64_t pk = ((uint64_t)(uint32_t)(t + 1) << 32) |
                          (uint64_t)__float_as_uint(hnew);
            __hip_atomic_store(&hbuf[((size_t)(t & 1)) * (NWG * 8) + wg * 8 + lane],
                               pk, __ATOMIC_RELAXED, __HIP_MEMORY_SCOPE_AGENT);
            out[(size_t)t * HDIM + obase + lane] = hnew;
        }
    }
}

// ---------------------------------------------------------------------------
extern "C" void kernel_launch(void* const* d_in, const int* in_sizes, int n_in,
                              void* d_out, int out_size, void* d_ws, size_t ws_size,
                              hipStream_t stream) {
    const float* obs   = (const float*)d_in[0];
    const float* act   = (const float*)d_in[1];
    const float* enc_w = (const float*)d_in[2];
    const float* enc_b = (const float*)d_in[3];
    const float* w_ih  = (const float*)d_in[4];
    const float* w_hh  = (const float*)d_in[5];
    const float* b_ih  = (const float*)d_in[6];
    const float* b_hh  = (const float*)d_in[7];
    float* out = (float*)d_out;

    // ws layout: [0, 32KB) tagged h double-buffer (2x256x8 u64); [64KB,..) z_seq
    uint64_t* hbuf  = (uint64_t*)d_ws;
    float*    z_seq = (float*)((char*)d_ws + 65536);

    hipMemsetAsync(hbuf, 0, 2 * NWG * 8 * sizeof(uint64_t), stream);

    encoder_kernel<<<dim3(8, 512), 256, 0, stream>>>(obs, enc_w, enc_b, z_seq);

    // NORMAL launch: capacity (>=4 blocks/CU at <=512 VGPR, 1024 slots) far
    // exceeds grid=256, so all WGs are co-resident; no cooperative needed.
    gru_kernel<<<dim3(NWG), dim3(64), 0, stream>>>(
        out, z_seq, act, w_ih, w_hh, b_ih, b_hh, hbuf);
}

// Round 12
// 110482.910 us; speedup vs baseline: 1.5424x; 1.5424x over previous
//
#include <hip/hip_runtime.h>
#include <stdint.h>

#define T_STEPS 32768
#define HDIM    1024
#define LDIM    512
#define ADIM    32
#define NWG     128   // workgroups in recurrence kernel
#define NOUT    8     // belief outputs per WG (NWG*NOUT == HDIM)

__device__ __forceinline__ float fast_sigmoid(float x) {
    float e = __expf(-x);
    return __builtin_amdgcn_rcpf(1.0f + e);
}
__device__ __forceinline__ float fast_tanh(float x) {
    // tanh(x) = 1 - 2/(1+e^(2x)); exact at +-inf, ~2ulp elsewhere
    float e = __expf(2.0f * x);
    return 1.0f - 2.0f * __builtin_amdgcn_rcpf(1.0f + e);
}

// ---------------------------------------------------------------------------
// Encoder: z[t,m] = tanh( sum_k obs[t,k]*enc_w[m,k] + enc_b[m] )
// ---------------------------------------------------------------------------
__global__ __launch_bounds__(256) void encoder_kernel(
    const float* __restrict__ obs,    // (T,128)
    const float* __restrict__ w,      // (512,128)
    const float* __restrict__ b,      // (512)
    float* __restrict__ z)            // (T,512)
{
    __shared__ float As[64][65];
    __shared__ float Bs[64][65];

    const int tile_n = blockIdx.x;  // 0..7   (m tiles)
    const int tile_t = blockIdx.y;  // 0..511 (t tiles)
    const int tid = threadIdx.x;
    const int ty = tid >> 4;
    const int tx = tid & 15;

    float acc[4][4] = {};

    for (int kt = 0; kt < 2; ++kt) {
        #pragma unroll
        for (int it = 0; it < 4; ++it) {
            int lin = it * 1024 + tid * 4;
            int r = lin >> 6, c = lin & 63;
            float4 va = *(const float4*)&obs[(size_t)(tile_t * 64 + r) * 128 + kt * 64 + c];
            As[r][c] = va.x; As[r][c+1] = va.y; As[r][c+2] = va.z; As[r][c+3] = va.w;
            float4 vb = *(const float4*)&w[(size_t)(tile_n * 64 + r) * 128 + kt * 64 + c];
            Bs[r][c] = vb.x; Bs[r][c+1] = vb.y; Bs[r][c+2] = vb.z; Bs[r][c+3] = vb.w;
        }
        __syncthreads();

        for (int k = 0; k < 64; ++k) {
            float av[4], bv[4];
            #pragma unroll
            for (int a = 0; a < 4; ++a) av[a] = As[ty * 4 + a][k];
            #pragma unroll
            for (int c = 0; c < 4; ++c) bv[c] = Bs[tx * 4 + c][k];
            #pragma unroll
            for (int a = 0; a < 4; ++a)
                #pragma unroll
                for (int c = 0; c < 4; ++c)
                    acc[a][c] = fmaf(av[a], bv[c], acc[a][c]);
        }
        __syncthreads();
    }

    #pragma unroll
    for (int a = 0; a < 4; ++a) {
        int row = tile_t * 64 + ty * 4 + a;
        #pragma unroll
        for (int c = 0; c < 4; ++c) {
            int col = tile_n * 64 + tx * 4 + c;
            z[(size_t)row * LDIM + col] = tanhf(acc[a][c] + b[col]);
        }
    }
}

// ---------------------------------------------------------------------------
// GRU recurrence. NWG x 256 threads, cooperative launch.
// R8 structure with ONE change: WAVE-LOCAL PUBLICATION, no B2.
//  - The 5-round butterfly leaves each group's reduced sums in ALL 32 lanes,
//    so gates run unguarded in every lane (group-uniform); 'hold' is carried
//    per-lane (uniform within a group).
//  - Each wave w owns outputs {wg*8+2w, wg*8+2w+1}. Lane 0 of the wave
//    fetches the sibling group's hnew with one intra-wave shfl and issues
//    TWO adjacent 8B tagged stores to the wave's own private 64B line:
//    exactly one writer per line, publication starts the moment each wave's
//    gates finish (no h_pub LDS stage, no B2 barrier, no cross-wave gather).
//    (16B atomic store is not lock-free on gfx950 -> two 8B atomics.)
//  - hbuf: (2 parities) x (128 WG x 4 waves) lines of 64B; first 16B used
//    ({tag|h} u64 x 2). Pollers poll 4 x 2x8B sparse loads per publisher.
// Tag/parity protocol identical to R8 (transitive safety unchanged).
// ---------------------------------------------------------------------------
__global__ __launch_bounds__(256, 1) void gru_kernel(
    float* __restrict__ out,          // (T, 1024) == beliefs
    const float* __restrict__ z_seq,  // (T, 512)
    const float* __restrict__ act,    // (T, 32)
    const float* __restrict__ w_ih,   // (3072, 544)
    const float* __restrict__ w_hh,   // (3072, 1024)
    const float* __restrict__ b_ih,   // (3072)
    const float* __restrict__ b_hh,   // (3072)
    uint64_t* __restrict__ hbuf)      // (2, 512, 8) u64 lines, zeroed
{
    __shared__ float h_lds[HDIM];
    __shared__ float z_lds[LDIM];
    __shared__ float a_lds[ADIM];

    const int tid  = threadIdx.x;
    const int wg   = blockIdx.x;
    const int grp  = tid >> 5;        // 0..7
    const int lane = tid & 31;
    const int wv   = tid >> 6;        // wave 0..3
    const int wl   = tid & 63;        // lane within wave
    const int i    = wg * NOUT + grp; // global output index 0..1023

    // ---- load weight slices into registers (once) and PIN them ----
    float whr[32], whz[32], whn[32];
    {
        const float* pr = &w_hh[(size_t)i * HDIM + lane];
        const float* pz = &w_hh[(size_t)(HDIM + i) * HDIM + lane];
        const float* pn = &w_hh[(size_t)(2 * HDIM + i) * HDIM + lane];
        #pragma unroll
        for (int j = 0; j < 32; ++j) {
            whr[j] = pr[32 * j]; whz[j] = pz[32 * j]; whn[j] = pn[32 * j];
        }
    }
    float wir[17], wiz[17], win[17];
    {
        const float* pr = &w_ih[(size_t)i * 544 + lane];
        const float* pz = &w_ih[(size_t)(HDIM + i) * 544 + lane];
        const float* pn = &w_ih[(size_t)(2 * HDIM + i) * 544 + lane];
        #pragma unroll
        for (int j = 0; j < 17; ++j) {
            wir[j] = pr[32 * j]; wiz[j] = pz[32 * j]; win[j] = pn[32 * j];
        }
    }
    #pragma unroll
    for (int j = 0; j < 32; ++j) {
        asm volatile("" : "+v"(whr[j]), "+v"(whz[j]), "+v"(whn[j]));
    }
    #pragma unroll
    for (int j = 0; j < 17; ++j) {
        asm volatile("" : "+v"(wir[j]), "+v"(wiz[j]), "+v"(win[j]));
    }

    // pre-merged biases for r/z (their ih+hh sums combine pre-sigmoid)
    const float bias_r = b_ih[i] + b_hh[i];
    const float bias_z = b_ih[HDIM + i] + b_hh[HDIM + i];
    const float bin_   = b_ih[2 * HDIM + i];
    const float bhn    = b_hh[2 * HDIM + i];

    for (int q = tid; q < HDIM; q += 256) h_lds[q] = 0.0f;
    float hold = 0.0f;   // per-lane copy of the group's own h (group-uniform)
    __syncthreads();

    for (int t = 0; t < T_STEPS; ++t) {
        if (tid < 128) {
            // ---- stage input-side data (overlaps other waves' h poll) ----
            float4 v = *(const float4*)&z_seq[(size_t)t * LDIM + tid * 4];
            *(float4*)&z_lds[tid * 4] = v;
            if (tid < ADIM) {
                a_lds[tid] = (t == 0) ? 0.0f : act[(size_t)(t - 1) * ADIM + tid];
            }
        } else if (t > 0) {
            // ---- poll publisher q's 4 wave-lines (2x8B each) of h(t-1) ----
            const int q = tid - 128;                 // 0..127 = publisher index
            const uint64_t* bp = hbuf + ((size_t)((t - 1) & 1)) * (512 * 8)
                                      + (size_t)q * (4 * 8);
            const uint32_t want = (uint32_t)t;
            uint64_t v0[4], v1[4];
            int done = 0;
            while (done != 0xF) {
                #pragma unroll
                for (int w = 0; w < 4; ++w) {
                    if (!(done & (1 << w))) {
                        v0[w] = __hip_atomic_load(bp + w * 8 + 0, __ATOMIC_RELAXED,
                                                  __HIP_MEMORY_SCOPE_AGENT);
                        v1[w] = __hip_atomic_load(bp + w * 8 + 1, __ATOMIC_RELAXED,
                                                  __HIP_MEMORY_SCOPE_AGENT);
                    }
                }
                #pragma unroll
                for (int w = 0; w < 4; ++w) {
                    if (!(done & (1 << w)) &&
                        (uint32_t)(v0[w] >> 32) == want &&
                        (uint32_t)(v1[w] >> 32) == want) {
                        done |= (1 << w);
                        float2 hp;
                        hp.x = __uint_as_float((uint32_t)v0[w]);
                        hp.y = __uint_as_float((uint32_t)v1[w]);
                        *(float2*)&h_lds[q * 8 + 2 * w] = hp;
                    }
                }
            }
        }
        __syncthreads();   // B1: h_lds/z_lds/a_lds ready (the only barrier)

        // ---- matvec partials: hh-side (1024) and ih-side (544) ----
        float sr = 0.f, sz = 0.f, sn = 0.f;
        #pragma unroll
        for (int j = 0; j < 32; ++j) {
            float hv = h_lds[lane + 32 * j];
            sr = fmaf(whr[j], hv, sr);
            sz = fmaf(whz[j], hv, sz);
            sn = fmaf(whn[j], hv, sn);
        }
        float gr = 0.f, gz = 0.f, gn = 0.f;
        #pragma unroll
        for (int j = 0; j < 16; ++j) {
            float xv = z_lds[lane + 32 * j];
            gr = fmaf(wir[j], xv, gr);
            gz = fmaf(wiz[j], xv, gz);
            gn = fmaf(win[j], xv, gn);
        }
        {
            float xa = a_lds[lane];
            gr = fmaf(wir[16], xa, gr);
            gz = fmaf(wiz[16], xa, gz);
            gn = fmaf(win[16], xa, gn);
        }

        float vr = sr + gr, vz = sz + gz;
        #pragma unroll
        for (int m = 16; m >= 1; m >>= 1) {
            vr += __shfl_xor(vr, m);
            vz += __shfl_xor(vz, m);
            sn += __shfl_xor(sn, m);
            gn += __shfl_xor(gn, m);
        }
        // butterfly leaves sums in ALL lanes of each 32-group

        // ---- gates unguarded (group-uniform in every lane) ----
        float r    = fast_sigmoid(vr + bias_r);
        float zg   = fast_sigmoid(vz + bias_z);
        float n    = fast_tanh(gn + bin_ + r * (sn + bhn));
        float hnew = (1.0f - zg) * n + zg * hold;
        hold = hnew;

        // ---- wave-local publication: lane 0 of each wave stores its wave's
        //      2 outputs as two adjacent 8B tagged stores (private line) ----
        float sib = __shfl(hnew, 32);   // group (2wv+1)'s hnew, valid at wl==0
        if (wl == 0) {
            uint64_t pk0 = ((uint64_t)(uint32_t)(t + 1) << 32) |
                           (uint64_t)__float_as_uint(hnew);
            uint64_t pk1 = ((uint64_t)(uint32_t)(t + 1) << 32) |
                           (uint64_t)__float_as_uint(sib);
            uint64_t* lp = hbuf + ((size_t)(t & 1)) * (512 * 8)
                                + (size_t)(wg * 4 + wv) * 8;
            __hip_atomic_store(lp + 0, pk0, __ATOMIC_RELAXED,
                               __HIP_MEMORY_SCOPE_AGENT);
            __hip_atomic_store(lp + 1, pk1, __ATOMIC_RELAXED,
                               __HIP_MEMORY_SCOPE_AGENT);
        } else if (wl == 4) {
            // out store off the critical path: this wave's 2 adjacent outputs
            float2 o; o.x = hnew; o.y = sib;
            *(float2*)&out[(size_t)t * HDIM + wg * NOUT + 2 * wv] = o;
        }
        // next iteration's B1 protects h_lds/z_lds reuse
    }
}

// ---------------------------------------------------------------------------
extern "C" void kernel_launch(void* const* d_in, const int* in_sizes, int n_in,
                              void* d_out, int out_size, void* d_ws, size_t ws_size,
                              hipStream_t stream) {
    const float* obs   = (const float*)d_in[0];
    const float* act   = (const float*)d_in[1];
    const float* enc_w = (const float*)d_in[2];
    const float* enc_b = (const float*)d_in[3];
    const float* w_ih  = (const float*)d_in[4];
    const float* w_hh  = (const float*)d_in[5];
    const float* b_ih  = (const float*)d_in[6];
    const float* b_hh  = (const float*)d_in[7];
    float* out = (float*)d_out;

    // ws layout: [0, 64KB) tagged h lines (2 x 512 x 64B) ; [128KB,..) z_seq
    uint64_t* hbuf  = (uint64_t*)d_ws;
    float*    z_seq = (float*)((char*)d_ws + 131072);

    (void)hipMemsetAsync(hbuf, 0, 65536, stream);

    encoder_kernel<<<dim3(8, 512), 256, 0, stream>>>(obs, enc_w, enc_b, z_seq);

    void* args[] = {(void*)&out, (void*)&z_seq, (void*)&act, (void*)&w_ih,
                    (void*)&w_hh, (void*)&b_ih, (void*)&b_hh, (void*)&hbuf};
    (void)hipLaunchCooperativeKernel((void*)gru_kernel, dim3(NWG), dim3(256),
                                     args, 0, stream);
}